// Round 7
// baseline (215.715 us; speedup 1.0000x reference)
//
#include <hip/hip_runtime.h>

typedef unsigned short u16;
typedef __attribute__((ext_vector_type(8))) __bf16 bf16x8;
typedef __attribute__((ext_vector_type(4))) float f32x4;

__device__ __forceinline__ u16 f2bf(float f) {
  union { float f; unsigned u; } x; x.f = f;
  unsigned r = x.u + 0x7fffu + ((x.u >> 16) & 1u);
  return (u16)(r >> 16);
}

#define GLD16(g, l) __builtin_amdgcn_global_load_lds( \
    (__attribute__((address_space(1))) void*)(size_t)(g), \
    (__attribute__((address_space(3))) void*)(l), 16, 0, 0)

// ---------------------------------------------------------------------------
__global__ __launch_bounds__(256) void cvt_f32_bf16(const float* __restrict__ in,
                                                    u16* __restrict__ out) {
  int i = blockIdx.x * 256 + threadIdx.x;
  float4 v = ((const float4*)in)[i];
  ushort4 o;
  o.x = f2bf(v.x); o.y = f2bf(v.y); o.z = f2bf(v.z); o.w = f2bf(v.w);
  ((ushort4*)out)[i] = o;
}

// in[R][C] fp32 -> out[perm(C)][R] bf16. PERM=1: c=h*288+d*3+w -> w*768+h*96+d
template <int PERM>
__global__ __launch_bounds__(256) void transpose_f32_bf16(const float* __restrict__ in,
                                                          u16* __restrict__ out,
                                                          int R, int C) {
  __shared__ u16 tile[32][33];
  int tilesC = C >> 5;
  int bc = blockIdx.x % tilesC, br = blockIdx.x / tilesC;
  int tx = threadIdx.x & 31, ty = threadIdx.x >> 5;
#pragma unroll
  for (int i = 0; i < 4; ++i)
    tile[ty + i * 8][tx] = f2bf(in[(size_t)(br * 32 + ty + i * 8) * C + bc * 32 + tx]);
  __syncthreads();
#pragma unroll
  for (int i = 0; i < 4; ++i) {
    int c = bc * 32 + ty + i * 8;
    int orow;
    if constexpr (PERM) {
      int which = c % 3, h = c / 288, d = (c % 288) / 3;
      orow = which * 768 + h * 96 + d;
    } else {
      orow = c;
    }
    out[(size_t)orow * R + br * 32 + tx] = tile[tx][ty + i * 8];
  }
}

// ---------------------------------------------------------------------------
// 256x256 GEMM, BK=32, 8 waves (2x4), 4-buffer LDS ring (128 KB), depth-3
// prefetch with COUNTED vmcnt (never 0 in steady state), 2 fine phases/tile
// {ds_reads || stage; barrier; lgkm0+pin; prio1 16-MFMA prio0; barrier},
// XOR-swizzled LDS reads (pre-swizzled global source, linear LDS dest).
// Hazard ledger (per-wave, 4 GLD16 per stage-call):
//  WAR: stage(t+3)->buf[(t-1)&3]; t-1's reads drained before its final barrier.
//  RAW: boundary vmcnt(8) leaves only stages (t+2),(t+3) outstanding => (t+1)
//       landed; following barrier makes it collective.
template <int EPI>
__global__ __launch_bounds__(512, 2) void gemm256(
    const u16* __restrict__ A, const u16* __restrict__ BT,
    const float* __restrict__ bias, int K, int lda, int ldb, int ldc,
    int tilesN, int cpx, size_t bstride, float* __restrict__ outf,
    u16* __restrict__ q_dst, u16* __restrict__ k_dst, u16* __restrict__ v_dst) {
  __shared__ u16 As[4][8192];   // [buf][256r][32c] bf16, 16 KB each
  __shared__ u16 Bs[4][8192];
  const int bid = blockIdx.x;
  const int swz = (bid & 7) * cpx + (bid >> 3);
  const int tr = swz / tilesN, tc = swz % tilesN;
  const int tid = threadIdx.x, lane = tid & 63, wv = tid >> 6;
  const int wr = wv >> 2, wc = wv & 3;
  const int l15 = lane & 15, lhi = lane >> 4;
  const int nt = K >> 5;                       // 24 K-tiles
  const int region = tc / 3;                   // EPI=0: 0=q,1=k,2=v

  BT += (size_t)((unsigned)(tr * 256) >> 10) * bstride;   // per-batch B (EPI=1)

  // staging sources: granule g = ch*512+tid; r=g>>2, c=g&3; pre-swizzled
  // source column c' = c ^ swz(r), swz(r)=(r^(r>>2))&3; LDS dest linear.
  const u16 *srcA0, *srcA1, *srcB0, *srcB1;
  {
    int g0 = tid,       r0 = g0 >> 2, c0 = (g0 & 3) ^ ((r0 ^ (r0 >> 2)) & 3);
    int g1 = 512 + tid, r1 = g1 >> 2, c1 = (g1 & 3) ^ ((r1 ^ (r1 >> 2)) & 3);
    srcA0 = A  + (size_t)(tr * 256 + r0) * lda + c0 * 8;
    srcA1 = A  + (size_t)(tr * 256 + r1) * lda + c1 * 8;
    srcB0 = BT + (size_t)(tc * 256 + r0) * ldb + c0 * 8;
    srcB1 = BT + (size_t)(tc * 256 + r1) * ldb + c1 * 8;
  }
  // swizzled LDS read offsets (u16 units)
  int offa[8], offb[4];
#pragma unroll
  for (int m = 0; m < 8; ++m) {
    int r = wr * 128 + m * 16 + l15;
    offa[m] = r * 32 + ((lhi ^ (r ^ (r >> 2))) & 3) * 8;
  }
#pragma unroll
  for (int n = 0; n < 4; ++n) {
    int r = wc * 64 + n * 16 + l15;
    offb[n] = r * 32 + ((lhi ^ (r ^ (r >> 2))) & 3) * 8;
  }

  // hoisted bias
  float bv4[4];
#pragma unroll
  for (int n = 0; n < 4; ++n) {
    int colg = tc * 256 + wc * 64 + n * 16 + l15;
    if constexpr (EPI == 0) {
      int lcol = colg - region * 768;
      bv4[n] = bias[(lcol / 96) * 288 + (lcol % 96) * 3 + region];
    } else {
      bv4[n] = bias[colg];
    }
  }

#define STAGE(t_) do { \
    u16* Ad_ = (u16*)As[(t_) & 3]; u16* Bd_ = (u16*)Bs[(t_) & 3]; \
    int ko_ = (t_) * 32; \
    GLD16(srcA0 + ko_, Ad_ + (wv * 64) * 8); \
    GLD16(srcA1 + ko_, Ad_ + (512 + wv * 64) * 8); \
    GLD16(srcB0 + ko_, Bd_ + (wv * 64) * 8); \
    GLD16(srcB1 + ko_, Bd_ + (512 + wv * 64) * 8); } while (0)

  bf16x8 af[4], bfv[4];
  f32x4 acc[8][4] = {};
#define CLUSTER16(MB) do { \
    __builtin_amdgcn_s_setprio(1); \
    _Pragma("unroll") for (int mm = 0; mm < 4; ++mm) \
    _Pragma("unroll") for (int nn = 0; nn < 4; ++nn) \
      acc[(MB) + mm][nn] = __builtin_amdgcn_mfma_f32_16x16x32_bf16( \
          af[mm], bfv[nn], acc[(MB) + mm][nn], 0, 0, 0); \
    __builtin_amdgcn_s_setprio(0); } while (0)
#define WAIT_LGKM_PIN() do { \
    asm volatile("s_waitcnt lgkmcnt(0)" ::: "memory"); \
    __builtin_amdgcn_sched_barrier(0); } while (0)

  // prologue: tiles 0,1,2 in flight (12 loads); vmcnt(8) -> tile 0 landed
  STAGE(0); STAGE(1); STAGE(2);
  asm volatile("s_waitcnt vmcnt(8)" ::: "memory");
  __builtin_amdgcn_s_barrier();

  for (int t = 0; t < nt; ++t) {
    const u16* Ab = As[t & 3];
    const u16* Bb = Bs[t & 3];
    // ---- Ph0: stage t+3; reads A0-3,B0-3; cluster rows 0-3
    if (t + 3 < nt) STAGE(t + 3);
#pragma unroll
    for (int m = 0; m < 4; ++m) af[m] = *(const bf16x8*)&Ab[offa[m]];
#pragma unroll
    for (int n = 0; n < 4; ++n) bfv[n] = *(const bf16x8*)&Bb[offb[n]];
    __builtin_amdgcn_s_barrier();
    WAIT_LGKM_PIN();
    CLUSTER16(0);
    __builtin_amdgcn_s_barrier();
    // ---- Ph1: reads A4-7; cluster rows 4-7; counted boundary
#pragma unroll
    for (int m = 0; m < 4; ++m) af[m] = *(const bf16x8*)&Ab[offa[4 + m]];
    __builtin_amdgcn_s_barrier();
    WAIT_LGKM_PIN();
    CLUSTER16(4);
    if (t + 3 < nt)      asm volatile("s_waitcnt vmcnt(8)" ::: "memory");
    else if (t + 2 < nt) asm volatile("s_waitcnt vmcnt(4)" ::: "memory");
    else if (t + 1 < nt) asm volatile("s_waitcnt vmcnt(0)" ::: "memory");
    __builtin_amdgcn_s_barrier();
  }
#undef STAGE
#undef CLUSTER16
#undef WAIT_LGKM_PIN

  u16* dst16 = region == 0 ? q_dst : (region == 1 ? k_dst : v_dst);
#pragma unroll
  for (int m = 0; m < 8; ++m)
#pragma unroll
    for (int n = 0; n < 4; ++n) {
      int colg = tc * 256 + wc * 64 + n * 16 + l15;
      int lcol = colg - region * 768;
#pragma unroll
      for (int r = 0; r < 4; ++r) {
        int rowg = tr * 256 + wr * 128 + m * 16 + lhi * 4 + r;
        if constexpr (EPI == 0)
          dst16[(size_t)rowg * ldc + lcol] = f2bf(acc[m][n][r] + bv4[n]);
        else
          outf[(size_t)rowg * ldc + colg] = acc[m][n][r] + bv4[n];
      }
    }
}

// ---------------------------------------------------------------------------
// Fused K/V transpose + M = K^T V.
// Grid 256 = bh(128) x d-half(2); 128 threads (2 waves).
// Per 128-row chunk: LDS-transpose K[n][dh*48..+48) -> kT[48][136] and
// V[n][0..96) -> vT[96][136], then MFMA accumulate (A=kT rows, B=vT rows).
__global__ __launch_bounds__(128) void kvm(const u16* __restrict__ kd,
                                           const u16* __restrict__ vd,
                                           u16* __restrict__ M) {
  __shared__ u16 kT[48][136];
  __shared__ u16 vT[96][136];
  const int bh = blockIdx.x >> 1, dh = blockIdx.x & 1;
  const int b = bh >> 3, h = bh & 7;
  const int tid = threadIdx.x, lane = tid & 63, nh = tid >> 6;  // wave = n-half
  const int l15 = lane & 15, lhi = lane >> 4;

  f32x4 acc[3][3] = {};

  for (int c = 0; c < 8; ++c) {
    const u16* kbase = kd + ((size_t)(b * 1024 + c * 128)) * 768 + h * 96 + dh * 48;
    const u16* vbase = vd + ((size_t)(b * 1024 + c * 128)) * 768 + h * 96;
    __syncthreads();   // previous chunk's MFMA reads done before overwrite
#pragma unroll
    for (int j = 0; j < 6; ++j) {           // K-half: 128 rows x 6 granules
      int idx = j * 128 + tid;
      int n = idx / 6, gg = idx % 6;
      uint4 v = *(const uint4*)(kbase + (size_t)n * 768 + gg * 8);
      const u16* e = (const u16*)&v;
#pragma unroll
      for (int q = 0; q < 8; ++q) kT[gg * 8 + q][n] = e[q];
    }
#pragma unroll
    for (int j = 0; j < 12; ++j) {          // V: 128 rows x 12 granules
      int idx = j * 128 + tid;
      int n = idx / 12, gg = idx % 12;
      uint4 v = *(const uint4*)(vbase + (size_t)n * 768 + gg * 8);
      const u16* e = (const u16*)&v;
#pragma unroll
      for (int q = 0; q < 8; ++q) vT[gg * 8 + q][n] = e[q];
    }
    __syncthreads();
#pragma unroll
    for (int ks = 0; ks < 4; ++ks) {
      bf16x8 a[3], bv[3];
#pragma unroll
      for (int mi = 0; mi < 3; ++mi)
        a[mi] = *(const bf16x8*)&kT[mi * 16 + l15][ks * 32 + lhi * 8];
#pragma unroll
      for (int nj = 0; nj < 3; ++nj)
        bv[nj] = *(const bf16x8*)&vT[nh * 48 + nj * 16 + l15][ks * 32 + lhi * 8];
#pragma unroll
      for (int mi = 0; mi < 3; ++mi)
#pragma unroll
        for (int nj = 0; nj < 3; ++nj)
          acc[mi][nj] = __builtin_amdgcn_mfma_f32_16x16x32_bf16(a[mi], bv[nj], acc[mi][nj], 0, 0, 0);
    }
  }

#pragma unroll
  for (int mi = 0; mi < 3; ++mi)
#pragma unroll
    for (int nj = 0; nj < 3; ++nj)
#pragma unroll
      for (int r = 0; r < 4; ++r)
        M[(size_t)bh * 9216 + (size_t)(dh * 48 + mi * 16 + lhi * 4 + r) * 96 +
          nh * 48 + nj * 16 + l15] = f2bf(acc[mi][nj][r]);
}

// ---------------------------------------------------------------------------
// GT[b][f][h*96+d] = sum_{d'} Wfc[h*96+d', f] * M[bh][d][d']
__global__ __launch_bounds__(512) void gkern(const u16* __restrict__ wfcT,
                                             const u16* __restrict__ M,
                                             u16* __restrict__ GT) {
  const int bh = blockIdx.x;
  const int b = bh >> 3, h = bh & 7;
  const int tid = threadIdx.x, lane = tid & 63, wv = tid >> 6;
  const int l15 = lane & 15, lhi = lane >> 4;
  const u16* Mb = M + (size_t)bh * 9216;
  f32x4 acc[6][6] = {};
#pragma unroll
  for (int ks = 0; ks < 3; ++ks) {
    bf16x8 a[6], bv[6];
#pragma unroll
    for (int fi = 0; fi < 6; ++fi)
      a[fi] = *(const bf16x8*)(wfcT + (size_t)(wv * 96 + fi * 16 + l15) * 768 +
                               h * 96 + ks * 32 + lhi * 8);
#pragma unroll
    for (int nj = 0; nj < 6; ++nj)
      bv[nj] = *(const bf16x8*)(Mb + (size_t)(nj * 16 + l15) * 96 + ks * 32 + lhi * 8);
#pragma unroll
    for (int fi = 0; fi < 6; ++fi)
#pragma unroll
      for (int nj = 0; nj < 6; ++nj)
        acc[fi][nj] = __builtin_amdgcn_mfma_f32_16x16x32_bf16(a[fi], bv[nj], acc[fi][nj], 0, 0, 0);
  }
#pragma unroll
  for (int fi = 0; fi < 6; ++fi)
#pragma unroll
    for (int nj = 0; nj < 6; ++nj)
#pragma unroll
      for (int r = 0; r < 4; ++r)
        GT[(size_t)b * 589824 + (size_t)(wv * 96 + fi * 16 + lhi * 4 + r) * 768 +
           h * 96 + nj * 16 + l15] = f2bf(acc[fi][nj][r]);
}

// ---------------------------------------------------------------------------
extern "C" void kernel_launch(void* const* d_in, const int* in_sizes, int n_in,
                              void* d_out, int out_size, void* d_ws, size_t ws_size,
                              hipStream_t stream) {
  const float* x    = (const float*)d_in[0];
  const float* Wqkv = (const float*)d_in[1];
  const float* bqkv = (const float*)d_in[2];
  const float* Wfc  = (const float*)d_in[3];
  const float* bfc  = (const float*)d_in[4];
  float* out = (float*)d_out;

  char* ws = (char*)d_ws;
  size_t off = 0;
  auto alloc = [&](size_t bytes) {
    void* p = ws + off;
    off += (bytes + 255) & ~(size_t)255;
    return p;
  };
  u16* xz    = (u16*)alloc(16384ull * 768 * 2);   // x_bf16 (dead after QKV GEMM)
  u16* wqkvT = (u16*)alloc(2304ull * 768 * 2);    // later M[128][96][96]
  u16* wfcT  = (u16*)alloc(768ull * 768 * 2);
  u16* qb    = (u16*)alloc(16384ull * 768 * 2);   // Q dense
  u16* kb    = (u16*)alloc(16384ull * 768 * 2);   // K dense
  u16* vb    = (u16*)alloc(16384ull * 768 * 2);   // V dense; later GT[16][768][768]

  cvt_f32_bf16<<<12288, 256, 0, stream>>>(x, xz);
  transpose_f32_bf16<1><<<(2304 / 32) * (768 / 32), 256, 0, stream>>>(Wqkv, wqkvT, 768, 2304);
  transpose_f32_bf16<0><<<(768 / 32) * (768 / 32), 256, 0, stream>>>(Wfc, wfcT, 768, 768);

  // QKV projection -> dense q/k/v buffers
  gemm256<0><<<576, 512, 0, stream>>>(xz, wqkvT, bqkv, 768, 768, 768, 768,
                                      9, 72, 0, nullptr, qb, kb, vb);

  // fused K/V transpose + M = K^T V   (M into the dead wqkvT region)
  kvm<<<256, 128, 0, stream>>>(kb, vb, (u16*)wqkvT);

  // GT_b = (M W_h)^T   (into vb, V dense dead after kvm)
  gkern<<<128, 512, 0, stream>>>(wfcT, (u16*)wqkvT, vb);

  // out = Q @ GT_b^T + bfc   (per-batch B matrix)
  gemm256<1><<<192, 512, 0, stream>>>(qb, vb, bfc, 768, 768, 768, 768,
                                      3, 24, 589824ull, out, nullptr, nullptr, nullptr);
}

// Round 8
// 173.355 us; speedup vs baseline: 1.2444x; 1.2444x over previous
//
#include <hip/hip_runtime.h>

typedef unsigned short u16;
typedef __attribute__((ext_vector_type(8))) __bf16 bf16x8;
typedef __attribute__((ext_vector_type(4))) float f32x4;

__device__ __forceinline__ u16 f2bf(float f) {
  union { float f; unsigned u; } x; x.f = f;
  unsigned r = x.u + 0x7fffu + ((x.u >> 16) & 1u);
  return (u16)(r >> 16);
}

#define GLD16(g, l) __builtin_amdgcn_global_load_lds( \
    (__attribute__((address_space(1))) void*)(size_t)(g), \
    (__attribute__((address_space(3))) void*)(l), 16, 0, 0)

// ---------------------------------------------------------------------------
__global__ __launch_bounds__(256) void cvt_f32_bf16(const float* __restrict__ in,
                                                    u16* __restrict__ out) {
  int i = blockIdx.x * 256 + threadIdx.x;
  float4 v = ((const float4*)in)[i];
  ushort4 o;
  o.x = f2bf(v.x); o.y = f2bf(v.y); o.z = f2bf(v.z); o.w = f2bf(v.w);
  ((ushort4*)out)[i] = o;
}

// in[R][C] fp32 -> out[perm(C)][R] bf16. PERM=1: c=h*288+d*3+w -> w*768+h*96+d
template <int PERM>
__global__ __launch_bounds__(256) void transpose_f32_bf16(const float* __restrict__ in,
                                                          u16* __restrict__ out,
                                                          int R, int C) {
  __shared__ u16 tile[32][33];
  int tilesC = C >> 5;
  int bc = blockIdx.x % tilesC, br = blockIdx.x / tilesC;
  int tx = threadIdx.x & 31, ty = threadIdx.x >> 5;
#pragma unroll
  for (int i = 0; i < 4; ++i)
    tile[ty + i * 8][tx] = f2bf(in[(size_t)(br * 32 + ty + i * 8) * C + bc * 32 + tx]);
  __syncthreads();
#pragma unroll
  for (int i = 0; i < 4; ++i) {
    int c = bc * 32 + ty + i * 8;
    int orow;
    if constexpr (PERM) {
      int which = c % 3, h = c / 288, d = (c % 288) / 3;
      orow = which * 768 + h * 96 + d;
    } else {
      orow = c;
    }
    out[(size_t)orow * R + br * 32 + tx] = tile[tx][ty + i * 8];
  }
}

// ---------------------------------------------------------------------------
// 256x256 GEMM, BK=64, 8 waves (2x4), dbuf=2, R6's proven 4-phase body, but
// with COUNTED vmcnt over half-tile stage units (T4):
//  units/tile: UA0 (A rows {0-63,128-191}, consumed Ph0+), UB0 (B rows
//  s*64+[0,32), Ph0+), UB1 (B rows s*64+[32,64), Ph1+), UA1 (Ph2+).
//  Issue 1 unit/phase at 1-tile lead: UA0@Ph0, UB0@Ph1, UB1@Ph2, UA1@Ph3.
//  RAW: entering any phase, exactly 2 units (4 loads) are newer than the unit
//       it needs -> vmcnt(4) at ends of Ph0/Ph1/Ph3 (tail vmcnt(2)/(0)),
//       before the barrier that precedes the dependent ds_reads.
//  WAR: unit(t+1) overwrites tile t-1 halves whose ds_reads drained at t-1's
//       lgkmcnt(0), two tiles prior.
template <int EPI>
__global__ __launch_bounds__(512, 2) void gemm256(
    const u16* __restrict__ A, const u16* __restrict__ BT,
    const float* __restrict__ bias, int K, int lda, int ldb, int ldc,
    int tilesN, int cpx, size_t bstride, float* __restrict__ outf,
    u16* __restrict__ q_dst, u16* __restrict__ k_dst, u16* __restrict__ v_dst) {
  __shared__ u16 As[2][16384];   // [buf][256r][64c] bf16, 32 KB each
  __shared__ u16 Bs[2][16384];
  const int bid = blockIdx.x;
  const int swz = (bid & 7) * cpx + (bid >> 3);
  const int tr = swz / tilesN, tc = swz % tilesN;
  const int tid = threadIdx.x, lane = tid & 63, wv = tid >> 6;
  const int wr = wv >> 2, wc = wv & 3;
  const int l15 = lane & 15, lhi = lane >> 4;
  const int nt = K >> 6;                       // 12 K-tiles
  const int region = tc / 3;                   // EPI=0: 0=q,1=k,2=v

  BT += (size_t)((unsigned)(tr * 256) >> 10) * bstride;   // per-batch B (EPI=1)

  // stage-unit source pointers + LDS row starts (pre-swizzled global source,
  // linear LDS dest; c' = c ^ ((row>>1)&7), same involution as the reads)
  const u16 *srcA[2][2], *srcB[2][2];
  int rsA[2][2], rsB[2][2];
#pragma unroll
  for (int h = 0; h < 2; ++h)
#pragma unroll
    for (int c = 0; c < 2; ++c) {
      int rs = c * 128 + h * 64 + wv * 8;                 // A unit rows
      int row = rs + (lane >> 3);
      rsA[h][c] = rs;
      srcA[h][c] = A + (size_t)(tr * 256 + row) * lda +
                   (((lane & 7) ^ ((row >> 1) & 7)) << 3);
      int L = c * 64 + wv * 8;                            // B unit linear idx
      int stripe = L >> 5;
      int rsb = stripe * 64 + h * 32 + (L & 31);          // h plays j for B
      int rowb = rsb + (lane >> 3);
      rsB[h][c] = rsb;
      srcB[h][c] = BT + (size_t)(tc * 256 + rowb) * ldb +
                   (((lane & 7) ^ ((rowb >> 1) & 7)) << 3);
    }

  // swizzled LDS read offsets (u16 units); k-slice 1 = offset ^ 32
  int offa[8], offb[4];
#pragma unroll
  for (int m = 0; m < 8; ++m) {
    int r = wr * 128 + m * 16 + l15;
    offa[m] = r * 64 + (lhi ^ ((r >> 1) & 7)) * 8;
  }
#pragma unroll
  for (int n = 0; n < 4; ++n) {
    int r = wc * 64 + n * 16 + l15;
    offb[n] = r * 64 + (lhi ^ ((r >> 1) & 7)) * 8;
  }

  // hoisted bias
  float bv4[4];
#pragma unroll
  for (int n = 0; n < 4; ++n) {
    int colg = tc * 256 + wc * 64 + n * 16 + l15;
    if constexpr (EPI == 0) {
      int lcol = colg - region * 768;
      bv4[n] = bias[(lcol / 96) * 288 + (lcol % 96) * 3 + region];
    } else {
      bv4[n] = bias[colg];
    }
  }

#define STAGE_UA(h_, t_) do { u16* Ad_ = (u16*)As[(t_) & 1]; int ko_ = (t_) * 64; \
    GLD16(srcA[h_][0] + ko_, Ad_ + rsA[h_][0] * 64); \
    GLD16(srcA[h_][1] + ko_, Ad_ + rsA[h_][1] * 64); } while (0)
#define STAGE_UB(j_, t_) do { u16* Bd_ = (u16*)Bs[(t_) & 1]; int ko_ = (t_) * 64; \
    GLD16(srcB[j_][0] + ko_, Bd_ + rsB[j_][0] * 64); \
    GLD16(srcB[j_][1] + ko_, Bd_ + rsB[j_][1] * 64); } while (0)

  bf16x8 af[4][2], bfv[4][2];
#define RD_A(m_, slot_) do { \
    af[slot_][0] = *(const bf16x8*)&Ab[offa[m_]]; \
    af[slot_][1] = *(const bf16x8*)&Ab[offa[m_] ^ 32]; } while (0)
#define RD_B(n_) do { \
    bfv[n_][0] = *(const bf16x8*)&Bb[offb[n_]]; \
    bfv[n_][1] = *(const bf16x8*)&Bb[offb[n_] ^ 32]; } while (0)

  f32x4 acc[8][4] = {};
#define CLUSTER(MB, NB) do { \
    __builtin_amdgcn_s_setprio(1); \
    _Pragma("unroll") for (int mm = 0; mm < 4; ++mm) \
    _Pragma("unroll") for (int nn = 0; nn < 2; ++nn) \
    _Pragma("unroll") for (int ks = 0; ks < 2; ++ks) \
      acc[(MB) + mm][(NB) + nn] = __builtin_amdgcn_mfma_f32_16x16x32_bf16( \
          af[mm][ks], bfv[(NB) + nn][ks], acc[(MB) + mm][(NB) + nn], 0, 0, 0); \
    __builtin_amdgcn_s_setprio(0); } while (0)
#define WAIT_LGKM_PIN() do { \
    asm volatile("s_waitcnt lgkmcnt(0)" ::: "memory"); \
    __builtin_amdgcn_sched_barrier(0); } while (0)

  // prologue: tile 0 units in age order UA0 < UB0 < UB1 < UA1
  STAGE_UA(0, 0); STAGE_UB(0, 0); STAGE_UB(1, 0); STAGE_UA(1, 0);
  asm volatile("s_waitcnt vmcnt(4)" ::: "memory");
  __builtin_amdgcn_s_barrier();

  for (int t = 0; t < nt; ++t) {
    const u16* Ab = As[t & 1];
    const u16* Bb = Bs[t & 1];
    // ---- Ph0: reads A0-3,B0-1 (UA0,UB0 certified); issue UA0(t+1)
    RD_A(0, 0); RD_A(1, 1); RD_A(2, 2); RD_A(3, 3);
    RD_B(0); RD_B(1);
    if (t + 1 < nt) STAGE_UA(0, t + 1);
    asm volatile("s_waitcnt lgkmcnt(8)" ::: "memory");
    __builtin_amdgcn_s_barrier();
    WAIT_LGKM_PIN();
    CLUSTER(0, 0);
    if (t + 1 < nt) asm volatile("s_waitcnt vmcnt(4)" ::: "memory");  // UB1(t)
    else            asm volatile("s_waitcnt vmcnt(2)" ::: "memory");
    __builtin_amdgcn_s_barrier();
    // ---- Ph1: reads B2-3 (UB1 certified); issue UB0(t+1)
    RD_B(2); RD_B(3);
    if (t + 1 < nt) STAGE_UB(0, t + 1);
    __builtin_amdgcn_s_barrier();
    WAIT_LGKM_PIN();
    CLUSTER(0, 2);
    if (t + 1 < nt) asm volatile("s_waitcnt vmcnt(4)" ::: "memory");  // UA1(t)
    else            asm volatile("s_waitcnt vmcnt(0)" ::: "memory");
    __builtin_amdgcn_s_barrier();
    // ---- Ph2: reads A4-7 (UA1 certified); issue UB1(t+1)
    RD_A(4, 0); RD_A(5, 1); RD_A(6, 2); RD_A(7, 3);
    if (t + 1 < nt) STAGE_UB(1, t + 1);
    __builtin_amdgcn_s_barrier();
    WAIT_LGKM_PIN();
    CLUSTER(4, 0);
    __builtin_amdgcn_s_barrier();
    // ---- Ph3: issue UA1(t+1); last cluster; certify UA0/UB0(t+1)
    if (t + 1 < nt) {
      STAGE_UA(1, t + 1);
      CLUSTER(4, 2);
      asm volatile("s_waitcnt vmcnt(4)" ::: "memory");
    } else {
      CLUSTER(4, 2);
    }
    __builtin_amdgcn_s_barrier();
  }
#undef STAGE_UA
#undef STAGE_UB
#undef RD_A
#undef RD_B
#undef CLUSTER
#undef WAIT_LGKM_PIN

  u16* dst16 = region == 0 ? q_dst : (region == 1 ? k_dst : v_dst);
#pragma unroll
  for (int m = 0; m < 8; ++m)
#pragma unroll
    for (int n = 0; n < 4; ++n) {
      int colg = tc * 256 + wc * 64 + n * 16 + l15;
      int lcol = colg - region * 768;
#pragma unroll
      for (int r = 0; r < 4; ++r) {
        int rowg = tr * 256 + wr * 128 + m * 16 + lhi * 4 + r;
        if constexpr (EPI == 0)
          dst16[(size_t)rowg * ldc + lcol] = f2bf(acc[m][n][r] + bv4[n]);
        else
          outf[(size_t)rowg * ldc + colg] = acc[m][n][r] + bv4[n];
      }
    }
}

// ---------------------------------------------------------------------------
// Fused K/V transpose + M = K^T V.
// Grid 256 = bh(128) x d-half(2); 128 threads (2 waves).
__global__ __launch_bounds__(128) void kvm(const u16* __restrict__ kd,
                                           const u16* __restrict__ vd,
                                           u16* __restrict__ M) {
  __shared__ u16 kT[48][136];
  __shared__ u16 vT[96][136];
  const int bh = blockIdx.x >> 1, dh = blockIdx.x & 1;
  const int b = bh >> 3, h = bh & 7;
  const int tid = threadIdx.x, lane = tid & 63, nh = tid >> 6;  // wave = n-half
  const int l15 = lane & 15, lhi = lane >> 4;

  f32x4 acc[3][3] = {};

  for (int c = 0; c < 8; ++c) {
    const u16* kbase = kd + ((size_t)(b * 1024 + c * 128)) * 768 + h * 96 + dh * 48;
    const u16* vbase = vd + ((size_t)(b * 1024 + c * 128)) * 768 + h * 96;
    __syncthreads();   // previous chunk's MFMA reads done before overwrite
#pragma unroll
    for (int j = 0; j < 6; ++j) {           // K-half: 128 rows x 6 granules
      int idx = j * 128 + tid;
      int n = idx / 6, gg = idx % 6;
      uint4 v = *(const uint4*)(kbase + (size_t)n * 768 + gg * 8);
      const u16* e = (const u16*)&v;
#pragma unroll
      for (int q = 0; q < 8; ++q) kT[gg * 8 + q][n] = e[q];
    }
#pragma unroll
    for (int j = 0; j < 12; ++j) {          // V: 128 rows x 12 granules
      int idx = j * 128 + tid;
      int n = idx / 12, gg = idx % 12;
      uint4 v = *(const uint4*)(vbase + (size_t)n * 768 + gg * 8);
      const u16* e = (const u16*)&v;
#pragma unroll
      for (int q = 0; q < 8; ++q) vT[gg * 8 + q][n] = e[q];
    }
    __syncthreads();
#pragma unroll
    for (int ks = 0; ks < 4; ++ks) {
      bf16x8 a[3], bv[3];
#pragma unroll
      for (int mi = 0; mi < 3; ++mi)
        a[mi] = *(const bf16x8*)&kT[mi * 16 + l15][ks * 32 + lhi * 8];
#pragma unroll
      for (int nj = 0; nj < 3; ++nj)
        bv[nj] = *(const bf16x8*)&vT[nh * 48 + nj * 16 + l15][ks * 32 + lhi * 8];
#pragma unroll
      for (int mi = 0; mi < 3; ++mi)
#pragma unroll
        for (int nj = 0; nj < 3; ++nj)
          acc[mi][nj] = __builtin_amdgcn_mfma_f32_16x16x32_bf16(a[mi], bv[nj], acc[mi][nj], 0, 0, 0);
    }
  }

#pragma unroll
  for (int mi = 0; mi < 3; ++mi)
#pragma unroll
    for (int nj = 0; nj < 3; ++nj)
#pragma unroll
      for (int r = 0; r < 4; ++r)
        M[(size_t)bh * 9216 + (size_t)(dh * 48 + mi * 16 + lhi * 4 + r) * 96 +
          nh * 48 + nj * 16 + l15] = f2bf(acc[mi][nj][r]);
}

// ---------------------------------------------------------------------------
// GT[b][f][h*96+d] = sum_{d'} Wfc[h*96+d', f] * M[bh][d][d']
__global__ __launch_bounds__(512) void gkern(const u16* __restrict__ wfcT,
                                             const u16* __restrict__ M,
                                             u16* __restrict__ GT) {
  const int bh = blockIdx.x;
  const int b = bh >> 3, h = bh & 7;
  const int tid = threadIdx.x, lane = tid & 63, wv = tid >> 6;
  const int l15 = lane & 15, lhi = lane >> 4;
  const u16* Mb = M + (size_t)bh * 9216;
  f32x4 acc[6][6] = {};
#pragma unroll
  for (int ks = 0; ks < 3; ++ks) {
    bf16x8 a[6], bv[6];
#pragma unroll
    for (int fi = 0; fi < 6; ++fi)
      a[fi] = *(const bf16x8*)(wfcT + (size_t)(wv * 96 + fi * 16 + l15) * 768 +
                               h * 96 + ks * 32 + lhi * 8);
#pragma unroll
    for (int nj = 0; nj < 6; ++nj)
      bv[nj] = *(const bf16x8*)(Mb + (size_t)(nj * 16 + l15) * 96 + ks * 32 + lhi * 8);
#pragma unroll
    for (int fi = 0; fi < 6; ++fi)
#pragma unroll
      for (int nj = 0; nj < 6; ++nj)
        acc[fi][nj] = __builtin_amdgcn_mfma_f32_16x16x32_bf16(a[fi], bv[nj], acc[fi][nj], 0, 0, 0);
  }
#pragma unroll
  for (int fi = 0; fi < 6; ++fi)
#pragma unroll
    for (int nj = 0; nj < 6; ++nj)
#pragma unroll
      for (int r = 0; r < 4; ++r)
        GT[(size_t)b * 589824 + (size_t)(wv * 96 + fi * 16 + lhi * 4 + r) * 768 +
           h * 96 + nj * 16 + l15] = f2bf(acc[fi][nj][r]);
}

// ---------------------------------------------------------------------------
extern "C" void kernel_launch(void* const* d_in, const int* in_sizes, int n_in,
                              void* d_out, int out_size, void* d_ws, size_t ws_size,
                              hipStream_t stream) {
  const float* x    = (const float*)d_in[0];
  const float* Wqkv = (const float*)d_in[1];
  const float* bqkv = (const float*)d_in[2];
  const float* Wfc  = (const float*)d_in[3];
  const float* bfc  = (const float*)d_in[4];
  float* out = (float*)d_out;

  char* ws = (char*)d_ws;
  size_t off = 0;
  auto alloc = [&](size_t bytes) {
    void* p = ws + off;
    off += (bytes + 255) & ~(size_t)255;
    return p;
  };
  u16* xz    = (u16*)alloc(16384ull * 768 * 2);   // x_bf16 (dead after QKV GEMM)
  u16* wqkvT = (u16*)alloc(2304ull * 768 * 2);    // later M[128][96][96]
  u16* wfcT  = (u16*)alloc(768ull * 768 * 2);
  u16* qb    = (u16*)alloc(16384ull * 768 * 2);   // Q dense
  u16* kb    = (u16*)alloc(16384ull * 768 * 2);   // K dense
  u16* vb    = (u16*)alloc(16384ull * 768 * 2);   // V dense; later GT[16][768][768]

  cvt_f32_bf16<<<12288, 256, 0, stream>>>(x, xz);
  transpose_f32_bf16<1><<<(2304 / 32) * (768 / 32), 256, 0, stream>>>(Wqkv, wqkvT, 768, 2304);
  transpose_f32_bf16<0><<<(768 / 32) * (768 / 32), 256, 0, stream>>>(Wfc, wfcT, 768, 768);

  // QKV projection -> dense q/k/v buffers
  gemm256<0><<<576, 512, 0, stream>>>(xz, wqkvT, bqkv, 768, 768, 768, 768,
                                      9, 72, 0, nullptr, qb, kb, vb);

  // fused K/V transpose + M = K^T V   (M into the dead wqkvT region)
  kvm<<<256, 128, 0, stream>>>(kb, vb, (u16*)wqkvT);

  // GT_b = (M W_h)^T   (into vb, V dense dead after kvm)
  gkern<<<128, 512, 0, stream>>>(wfcT, (u16*)wqkvT, vb);

  // out = Q @ GT_b^T + bfc   (per-batch B matrix)
  gemm256<1><<<192, 512, 0, stream>>>(qb, vb, bfc, 768, 768, 768, 768,
                                      3, 24, 589824ull, out, nullptr, nullptr, nullptr);
}